// Round 4
// baseline (95.271 us; speedup 1.0000x reference)
//
#include <hip/hip_runtime.h>
#include <math.h>

#define NQ   4
#define NH   8
#define NL   2
#define DIM  16   // 2^NQ
#define EMB  32
#define TPB  64   // tokens per block
#define EVP  33   // evs[t][k] pad: bank (t+k)%32 -> max 2-way (free)

// Constant-address-space alias: loads through this pointer with a
// wave-uniform address compile to s_load (SMEM pipe, SGPR result) instead
// of per-lane global_load. AS(4) == constant AS on amdgcn; same physical
// address space as global, cast via integer.
using cfloat = const __attribute__((address_space(4))) float;
__device__ __forceinline__ cfloat* cptr(const float* p) {
    return (cfloat*)(unsigned long long)p;
}

// ---------------------------------------------------------------------------
// Setup: per-head 16x16 unitary for the parameterized circuit. 128 threads:
// (head h, basis column col). Qubit q <-> bit (3-q). Fully unrolled ->
// static register indices. Layout: Ur[h][j][k] at ws[(h*16+j)*16+k],
// Ui at ws+2048.
// ---------------------------------------------------------------------------
__global__ void build_unitaries_kernel(const float* __restrict__ params,
                                       float* __restrict__ Uws) {
    int tid = threadIdx.x;          // 0..127
    int h   = tid >> 4;
    int col = tid & 15;

    float re[DIM], im[DIM];
#pragma unroll
    for (int j = 0; j < DIM; ++j) { re[j] = (j == col) ? 1.f : 0.f; im[j] = 0.f; }

#pragma unroll
    for (int l = 0; l < NL; ++l) {
#pragma unroll
        for (int q = 0; q < NQ; ++q) {
            const float* p = params + ((h * NL + l) * NQ + q) * 3;
            const int m = 1 << (3 - q);
            // RX
            {
                float s, c; __sincosf(0.5f * p[0], &s, &c);
#pragma unroll
                for (int j = 0; j < DIM; ++j) {
                    if (j & m) continue;
                    const int j1 = j | m;
                    float r0 = re[j], i0 = im[j], r1 = re[j1], i1 = im[j1];
                    re[j]  = c * r0 + s * i1;
                    im[j]  = c * i0 - s * r1;
                    re[j1] = s * i0 + c * r1;
                    im[j1] = -s * r0 + c * i1;
                }
            }
            // RY
            {
                float s, c; __sincosf(0.5f * p[1], &s, &c);
#pragma unroll
                for (int j = 0; j < DIM; ++j) {
                    if (j & m) continue;
                    const int j1 = j | m;
                    float r0 = re[j], i0 = im[j], r1 = re[j1], i1 = im[j1];
                    re[j]  = c * r0 - s * r1;
                    im[j]  = c * i0 - s * i1;
                    re[j1] = s * r0 + c * r1;
                    im[j1] = s * i0 + c * i1;
                }
            }
            // RZ
            {
                float s, c; __sincosf(0.5f * p[2], &s, &c);
#pragma unroll
                for (int j = 0; j < DIM; ++j) {
                    if (j & m) continue;
                    const int j1 = j | m;
                    float r0 = re[j], i0 = im[j], r1 = re[j1], i1 = im[j1];
                    re[j]  = c * r0 + s * i0;
                    im[j]  = c * i0 - s * r0;
                    re[j1] = c * r1 - s * i1;
                    im[j1] = c * i1 + s * r1;
                }
            }
        }
        // CNOT ring: (0,1),(1,2),(2,3),(3,0)
#pragma unroll
        for (int e = 0; e < NQ; ++e) {
            const int cm = 1 << (3 - e), tm = 1 << (3 - ((e + 1) & 3));
#pragma unroll
            for (int j = 0; j < DIM; ++j) {
                if ((j & cm) && !(j & tm)) {
                    const int j1 = j | tm;
                    float tr = re[j]; re[j] = re[j1]; re[j1] = tr;
                    float ti = im[j]; im[j] = im[j1]; im[j1] = ti;
                }
            }
        }
    }
#pragma unroll
    for (int j = 0; j < DIM; ++j) {
        Uws[(h * DIM + j) * DIM + col]        = re[j];
        Uws[2048 + (h * DIM + j) * DIM + col] = im[j];
    }
}

// ---------------------------------------------------------------------------
// Main: block = 512 threads = 8 waves, 64 tokens, no guards (exact grid).
// Phase 1: wave w = head w; lane = token. x read direct (float4, L1 absorbs
// the 8x line re-reads). U through AS(4) + uniform address -> s_load; the
// 512-FMA matvec uses SGPR operands. ev -> evs[t][k] (pad 33, 2-way banks).
// Phase 2: wave w = output group e=4w..4w+3 (wave-uniform -> W,b s_loads),
// lane = token; evs reads b32 at bank (t+k)%32 (2-way, free). float4 store;
// the 8 waves of a block fill each token's 128B line -> L2 merges.
// ---------------------------------------------------------------------------
__global__ __launch_bounds__(512, 4)
void qmha_kernel(const float* __restrict__ x,
                 const float* __restrict__ Uws,
                 const float* __restrict__ W,
                 const float* __restrict__ bvec,
                 float* __restrict__ out) {
    __shared__ float evs[TPB * EVP];   // evs[t][k], k = h*4+q

    const int tid  = threadIdx.x;
    const int tok0 = blockIdx.x * TPB;
    const int lane = tid & 63;

    // ---- phase 1: quantum circuit; wave = head, lane = token ----
    {
        const int h = __builtin_amdgcn_readfirstlane(tid >> 6);
        const int tok = tok0 + lane;

        const float4 xa = *(const float4*)(x + (size_t)tok * EMB + h * NQ);
        float c0, s0, c1, s1, c2, s2, c3, s3;
        __sincosf(0.5f * xa.x, &s0, &c0);
        __sincosf(0.5f * xa.y, &s1, &c1);
        __sincosf(0.5f * xa.z, &s2, &c2);
        __sincosf(0.5f * xa.w, &s3, &c3);

        // psi0[j] = f0[b3] f1[b2] f2[b1] f3[b0], qubit q <-> bit (3-q)
        float p01[4], p23[4], a[DIM];
        p01[0] = c0 * c1; p01[1] = c0 * s1; p01[2] = s0 * c1; p01[3] = s0 * s1;
        p23[0] = c2 * c3; p23[1] = c2 * s3; p23[2] = s2 * c3; p23[3] = s2 * s3;
#pragma unroll
        for (int j = 0; j < DIM; ++j) a[j] = p01[j >> 2] * p23[j & 3];

        cfloat* Ur = cptr(Uws + h * 256);
        cfloat* Ui = cptr(Uws + 2048 + h * 256);

        float ev0 = 0.f, ev1 = 0.f, ev2 = 0.f, ev3 = 0.f;
#pragma unroll
        for (int j = 0; j < DIM; ++j) {
            float ar = 0.f, ai = 0.f;
#pragma unroll
            for (int k = 0; k < DIM; ++k) {
                ar = fmaf(Ur[j * DIM + k], a[k], ar);
                ai = fmaf(Ui[j * DIM + k], a[k], ai);
            }
            const float pj = ar * ar + ai * ai;
            ev0 += (j & 8) ? -pj : pj;
            ev1 += (j & 4) ? -pj : pj;
            ev2 += (j & 2) ? -pj : pj;
            ev3 += (j & 1) ? -pj : pj;
        }

        evs[lane * EVP + h * 4 + 0] = ev0;
        evs[lane * EVP + h * 4 + 1] = ev1;
        evs[lane * EVP + h * 4 + 2] = ev2;
        evs[lane * EVP + h * 4 + 3] = ev3;
    }
    __syncthreads();

    // ---- phase 2: wave = 4-output group (uniform W rows), lane = token ----
    {
        const int w  = __builtin_amdgcn_readfirstlane(tid >> 6);
        const int e0 = w * 4;

        cfloat* Wr = cptr(W);
        cfloat* bc = cptr(bvec);

        float o0 = bc[e0 + 0], o1 = bc[e0 + 1], o2 = bc[e0 + 2], o3 = bc[e0 + 3];
#pragma unroll
        for (int k = 0; k < EMB; ++k) {
            const float evk = evs[lane * EVP + k];
            o0 = fmaf(Wr[(e0 + 0) * EMB + k], evk, o0);
            o1 = fmaf(Wr[(e0 + 1) * EMB + k], evk, o1);
            o2 = fmaf(Wr[(e0 + 2) * EMB + k], evk, o2);
            o3 = fmaf(Wr[(e0 + 3) * EMB + k], evk, o3);
        }
        float4 v; v.x = o0; v.y = o1; v.z = o2; v.w = o3;
        *(float4*)(out + (size_t)(tok0 + lane) * EMB + e0) = v;
    }
}

extern "C" void kernel_launch(void* const* d_in, const int* in_sizes, int n_in,
                              void* d_out, int out_size, void* d_ws, size_t ws_size,
                              hipStream_t stream) {
    const float* x      = (const float*)d_in[0];
    const float* params = (const float*)d_in[1];
    const float* W_out  = (const float*)d_in[2];
    const float* b_out  = (const float*)d_in[3];
    float*       out    = (float*)d_out;
    float*       Uws    = (float*)d_ws;   // 4096 floats = 16 KB

    const int ntok = in_sizes[0] / EMB;   // B*S = 131072, divisible by TPB

    hipLaunchKernelGGL(build_unitaries_kernel, dim3(1), dim3(128), 0, stream,
                       params, Uws);

    hipLaunchKernelGGL(qmha_kernel, dim3(ntok / TPB), dim3(512), 0, stream,
                       x, Uws, W_out, b_out, out);
}